// Round 10
// baseline (689.091 us; speedup 1.0000x reference)
//
#include <hip/hip_runtime.h>
#include <hip/hip_cooperative_groups.h>
#include <math.h>

// Sparsemax along axis 0 of z = -exp(a)*x, x: (4096, 8192) f32 row-major.
//
// R11: single cooperative kernel (4 phases) + one pure-write memset. 6 -> 2
// dispatches.
// R10 post-mortem: fusing the 128MiB zero-fill INTO the read pass cost +25us
// (mixed-direction stream is slower than two pure streams) -> memset(out)
// stays separate. R9 budget: ~104us of dispatches vs 41us HBM floor; the
// slack is glue (6 launches, pminx round-trip, separate solve). Collapse all
// compute into one cooperative kernel with grid.sync() between phases:
//   P1: slab (16-row) col-min partials -- THE sequential HBM read of x
//       (identical geometry to R9's k_pmax); prologue zeroes cnt.
//   P2: blocks 0..7 reduce 256 partials -> thrx[col] = (s*minx-1.000002)/s
//       (x-units; z > colmax-1 <=> x < thrx, s<0; margin keeps the candidate
//       set a strict SUPERSET of the support under f32 rounding).
//   P3: slab re-read (L3-hot, all 128MiB fits the 256MiB L3), scatter
//       (z,row) candidates for x < thrx; ~4.5/col, CAPC=64.
//   P4: 2 cols per wave: exact Michelot on <=64 candidates (1 slot/lane),
//       scatter ~5 nonzeros over pre-zeroed out. K>CAPC -> exact full-column
//       fallback (correctness never depends on statistics).
// Grid = 256 blocks x 1024 thr = 1 block/CU: cooperative co-residency holds.
//
// ws: [0,512K) cnt int[8192*16]; [512K,544K) thrx f32[8192];
//     [1M,9M) pminx f32[256][8192]; [9M,13M) cand float2[8192][64].

namespace cg = cooperative_groups;

constexpr int ROWS = 4096;
constexpr int COLS = 8192;
constexpr int CAPC = 64;           // candidate slots per column
constexpr int CPAD = 16;           // cnt stride (ints) = one 64B line per col
constexpr int SLAB = 16;           // rows per block slab
constexpr int NSLAB = ROWS / SLAB; // 256 blocks

__global__ __launch_bounds__(1024, 1)
void k_fused(const float* __restrict__ x, const float* __restrict__ a,
             int* __restrict__ cnt, float* __restrict__ pminx,
             float* __restrict__ thrx, float2* __restrict__ cand,
             float* __restrict__ out)
{
    cg::grid_group grid = cg::this_grid();
    __shared__ float tl[COLS];      // 32 KB thresholds (phase 3)

    const int t = threadIdx.x;
    const int b = blockIdx.x;

    // fused memset(cnt): 256 blocks x 128 int4 = 512 KB
    if (t < 128)
        reinterpret_cast<int4*>(cnt)[b * 128 + t] = make_int4(0, 0, 0, 0);

    const float s   = -expf(a[0]);  // s < 0 always
    const long row0 = (long)b * SLAB;

    // ---- P1: slab col-min partials (pure sequential HBM read) ----
    float m0=3e38f,m1=3e38f,m2=3e38f,m3=3e38f,
          m4=3e38f,m5=3e38f,m6=3e38f,m7=3e38f;
    for (int r = 0; r < SLAB; ++r) {
        const long rb = (row0 + r) * COLS;
        float4 v = *reinterpret_cast<const float4*>(x + rb + t * 4);
        m0 = fminf(m0, v.x); m1 = fminf(m1, v.y);
        m2 = fminf(m2, v.z); m3 = fminf(m3, v.w);
        v = *reinterpret_cast<const float4*>(x + rb + 4096 + t * 4);
        m4 = fminf(m4, v.x); m5 = fminf(m5, v.y);
        m6 = fminf(m6, v.z); m7 = fminf(m7, v.w);
    }
    *reinterpret_cast<float4*>(pminx + (long)b * COLS + t * 4) =
        make_float4(m0, m1, m2, m3);
    *reinterpret_cast<float4*>(pminx + (long)b * COLS + 4096 + t * 4) =
        make_float4(m4, m5, m6, m7);

    __threadfence();
    grid.sync();

    // ---- P2: blocks 0..7 reduce partials -> per-col threshold (x-units) ----
    if (b < 8) {
        const int col = b * 1024 + t;
        float mm = 3e38f;
        for (int p = 0; p < NSLAB; ++p)
            mm = fminf(mm, pminx[(long)p * COLS + col]);   // coalesced
        thrx[col] = (s * mm - 1.000002f) / s;
    }

    __threadfence();
    grid.sync();

    // ---- P3: slab re-read (L3-hot), scatter candidates ----
    for (int i = t; i < COLS / 4; i += 1024)
        reinterpret_cast<float4*>(tl)[i] =
            reinterpret_cast<const float4*>(thrx)[i];
    __syncthreads();
    for (int r = 0; r < SLAB; ++r) {
        const int  row = (int)row0 + r;
        const long rb  = (long)row * COLS;
#pragma unroll
        for (int ch = 0; ch < 2; ++ch) {
            const int col = ch * 4096 + t * 4;
            const float4 v  = *reinterpret_cast<const float4*>(x + rb + col);
            const float4 th = *reinterpret_cast<const float4*>(tl + col);
            if (v.x < th.x) { int i = atomicAdd(&cnt[(col + 0) * CPAD], 1);
                if (i < CAPC) cand[(long)(col + 0) * CAPC + i] =
                    make_float2(s * v.x, __int_as_float(row)); }
            if (v.y < th.y) { int i = atomicAdd(&cnt[(col + 1) * CPAD], 1);
                if (i < CAPC) cand[(long)(col + 1) * CAPC + i] =
                    make_float2(s * v.y, __int_as_float(row)); }
            if (v.z < th.z) { int i = atomicAdd(&cnt[(col + 2) * CPAD], 1);
                if (i < CAPC) cand[(long)(col + 2) * CAPC + i] =
                    make_float2(s * v.z, __int_as_float(row)); }
            if (v.w < th.w) { int i = atomicAdd(&cnt[(col + 3) * CPAD], 1);
                if (i < CAPC) cand[(long)(col + 3) * CAPC + i] =
                    make_float2(s * v.w, __int_as_float(row)); }
        }
    }

    __threadfence();
    grid.sync();

    // ---- P4: 2 cols per wave, exact Michelot + scatter ----
    const int lane = t & 63;
    const int W    = (b << 4) | (t >> 6);   // global wave id [0, 4096)
#pragma unroll
    for (int q = 0; q < 2; ++q) {
        const int col = W * 2 + q;
        const int K   = cnt[col * CPAD];
        if (K <= CAPC) {
            float v = -3.3e38f; int row = 0;
            if (lane < K) {
                const float2 p = cand[(long)col * CAPC + lane];
                v = p.x; row = __float_as_int(p.y);
            }
            float tau = -3.0e38f, prev = 0.f;
            for (int it = 0; it < CAPC + 4; ++it) {
                const bool act = v > tau;
                float ss = act ? v : 0.f;
                float sc = act ? 1.f : 0.f;
#pragma unroll
                for (int m = 1; m < 64; m <<= 1) {
                    ss += __shfl_xor(ss, m, 64);
                    sc += __shfl_xor(sc, m, 64);
                }
                tau = (ss - 1.0f) / sc;     // sc >= 1 (col max is a candidate)
                if (sc == prev) break;
                prev = sc;
            }
            if (v > tau) out[(long)row * COLS + col] = v - tau;  // out pre-zeroed
        } else {
            // overflow fallback: exact Michelot over the full column + scatter
            float tau = -3.0e38f, prev = 0.f;
            for (int it = 0; it < 256; ++it) {
                float ss = 0.f, sc = 0.f;
                for (int i = 0; i < ROWS / 64; ++i) {
                    const float zz = s * x[(long)(lane + i * 64) * COLS + col];
                    if (zz > tau) { ss += zz; sc += 1.f; }
                }
#pragma unroll
                for (int m = 1; m < 64; m <<= 1) {
                    ss += __shfl_xor(ss, m, 64);
                    sc += __shfl_xor(sc, m, 64);
                }
                tau = (ss - 1.0f) / sc;
                if (sc == prev) break;
                prev = sc;
            }
            for (int i = 0; i < ROWS / 64; ++i) {
                const long r = lane + i * 64;
                const float zz = s * x[r * COLS + col];
                if (zz > tau) out[r * COLS + col] = zz - tau;
            }
        }
    }
}

extern "C" void kernel_launch(void* const* d_in, const int* in_sizes, int n_in,
                              void* d_out, int out_size, void* d_ws, size_t ws_size,
                              hipStream_t stream) {
    const float* x = (const float*)d_in[0];
    const float* a = (const float*)d_in[1];
    float* out = (float*)d_out;

    char*   ws    = (char*)d_ws;
    int*    cnt   = (int*)ws;                        // 512 KB (padded counters)
    float*  thrx  = (float*)(ws + 512 * 1024);       // 32 KB
    float*  pminx = (float*)(ws + 1024 * 1024);      // 8 MiB
    float2* cand  = (float2*)(ws + 9 * 1024 * 1024); // 4 MiB

    // pure-write stream first (R10 lesson: never mix it into a read pass)
    hipMemsetAsync(out, 0, (size_t)ROWS * COLS * sizeof(float), stream);

    void* args[] = {(void*)&x, (void*)&a, (void*)&cnt, (void*)&pminx,
                    (void*)&thrx, (void*)&cand, (void*)&out};
    hipLaunchCooperativeKernel((const void*)k_fused, dim3(NSLAB), dim3(1024),
                               args, 0, stream);
}

// Round 11
// 258.598 us; speedup vs baseline: 2.6647x; 2.6647x over previous
//
#include <hip/hip_runtime.h>
#include <math.h>

// Sparsemax along axis 0 of z = -exp(a)*x, x: (4096, 8192) f32 row-major.
//
// R12: slab-pruned gather — the filter pass is GONE.
// R11 post-mortem: cooperative grid.sync() costs ~150us each on this 8-XCD
// chip (device-scope L2 flush across non-coherent XCDs): k_fused ran 526us
// at 1% VALU with memory-insensitive timing. Never grid.sync in a hot path;
// kernel boundaries provide ordering for ~launch-gap cost.
//
// Structure (3 dispatches):
//   memset(out): pure 128 MiB write stream (R10 lesson: never mix
//       directions in one pass).
//   k_pmax: R9-proven geometry. 256 blocks x 1024 thr; block = 16-row slab
//       read fully sequentially (512 KB); per-thread col-min over its 8
//       owned cols -> pminx[slab][col] (8 MiB, coalesced).
//   k_solve: one wave per column.
//       (1) scan 256 slabmins (4 strided loads/lane, L2/L3-hot) ->
//           butterfly -> colmin; thr = colmin + (1+eps)/|s| in x-units
//           (z > colmax_z - 1 <=> x < thr, s<0; eps covers f32 rounding so
//           the candidate set is a strict SUPERSET of the support).
//       (2) a slab can contain a candidate only if slabmin < thr
//           (~2-3 slabs/col): ballot-walk those slabs; lanes 0..15 gather
//           the slab's 16 elements, compact (z,row) pairs into LDS via
//           ballot prefix (no atomics anywhere).
//       (3) exact Michelot on <=64 candidates (1 slot/lane), scatter the
//           ~5 nonzeros over pre-zeroed out.
//       K > 64 -> exact full-column fallback (correctness never
//       statistical).
// Traffic: 128 MiB HBM read + 128 MiB HBM write (both mandatory) + 8 MiB
// pminx round-trip + ~2 MiB gather. No 128 MiB L3 re-read.
//
// ws: [0, 8M) pminx f32[256][8192].

constexpr int ROWS  = 4096;
constexpr int COLS  = 8192;
constexpr int SLAB  = 16;            // rows per slab
constexpr int NSLAB = ROWS / SLAB;   // 256
constexpr int CAPW  = 64;            // candidate capacity per column (1/lane)

// ---------------- A: sequential col-min slab partials ----------------
__global__ __launch_bounds__(1024)
void k_pmax(const float* __restrict__ x, float* __restrict__ pminx)
{
    const int t = threadIdx.x;
    const int b = blockIdx.x;
    const long row0 = (long)b * SLAB;

    float m0=3e38f,m1=3e38f,m2=3e38f,m3=3e38f,
          m4=3e38f,m5=3e38f,m6=3e38f,m7=3e38f;
    for (int r = 0; r < SLAB; ++r) {
        const long rb = (row0 + r) * COLS;
        float4 v = *reinterpret_cast<const float4*>(x + rb + t * 4);
        m0 = fminf(m0, v.x); m1 = fminf(m1, v.y);
        m2 = fminf(m2, v.z); m3 = fminf(m3, v.w);
        v = *reinterpret_cast<const float4*>(x + rb + 4096 + t * 4);
        m4 = fminf(m4, v.x); m5 = fminf(m5, v.y);
        m6 = fminf(m6, v.z); m7 = fminf(m7, v.w);
    }
    *reinterpret_cast<float4*>(pminx + (long)b * COLS + t * 4) =
        make_float4(m0, m1, m2, m3);
    *reinterpret_cast<float4*>(pminx + (long)b * COLS + 4096 + t * 4) =
        make_float4(m4, m5, m6, m7);
}

// -------- B: per-column wave — prune slabs, gather, Michelot, scatter ------
__global__ __launch_bounds__(256, 4)
void k_solve(const float* __restrict__ x, const float* __restrict__ a,
             const float* __restrict__ pminx, float* __restrict__ out)
{
    __shared__ float scand[4][CAPW];
    __shared__ int   srow[4][CAPW];

    const int t    = threadIdx.x;
    const int lane = t & 63;
    const int w    = t >> 6;
    const int col  = blockIdx.x * 4 + w;
    const float s  = -expf(a[0]);           // s < 0 always

    // (1) scan 256 slab minima -> colmin
    float sm[4];
#pragma unroll
    for (int i = 0; i < 4; ++i)
        sm[i] = pminx[(long)(lane + 64 * i) * COLS + col];
    float mn = fminf(fminf(sm[0], sm[1]), fminf(sm[2], sm[3]));
#pragma unroll
    for (int m = 1; m < 64; m <<= 1) mn = fminf(mn, __shfl_xor(mn, m, 64));
    // x < thr  <=>  z > colmax_z - 1 (with 2e-6 relative margin)
    const float thr = mn - 1.000002f / s;

    // (2) ballot-walk qualifying slabs, compact candidates into LDS
    int K = 0;
#pragma unroll
    for (int i = 0; i < 4; ++i) {
        unsigned long long bm = __ballot(sm[i] < thr);
        while (bm) {
            const int bit  = __ffsll((long long)bm) - 1;
            bm &= bm - 1;
            const int slab = 64 * i + bit;
            const int row  = slab * SLAB + lane;
            float xv = 0.f; bool c = false;
            if (lane < SLAB) {
                xv = x[(long)row * COLS + col];
                c  = xv < thr;
            }
            const unsigned long long cb = __ballot(c);
            const int pos = K + __popcll(cb & ((1ull << lane) - 1ull));
            if (c && pos < CAPW) { scand[w][pos] = s * xv; srow[w][pos] = row; }
            K += __popcll(cb);
        }
    }

    // (3) exact Michelot + scatter
    if (K <= CAPW) {
        float v = -3.3e38f; int row = 0;
        if (lane < K) { v = scand[w][lane]; row = srow[w][lane]; }
        float tau = -3.0e38f, prev = 0.f;
        for (int it = 0; it < CAPW + 4; ++it) {
            const bool act = v > tau;
            float ss = act ? v : 0.f;
            float sc = act ? 1.f : 0.f;
#pragma unroll
            for (int m = 1; m < 64; m <<= 1) {
                ss += __shfl_xor(ss, m, 64);
                sc += __shfl_xor(sc, m, 64);
            }
            tau = (ss - 1.0f) / sc;          // sc >= 1 (col min is a candidate)
            if (sc == prev) break;
            prev = sc;
        }
        if (v > tau) out[(long)row * COLS + col] = v - tau;   // out pre-zeroed
    } else {
        // overflow fallback: exact Michelot over the full column + scatter
        float tau = -3.0e38f, prev = 0.f;
        for (int it = 0; it < 256; ++it) {
            float ss = 0.f, sc = 0.f;
            for (int i = 0; i < ROWS / 64; ++i) {
                const float zz = s * x[(long)(lane + i * 64) * COLS + col];
                if (zz > tau) { ss += zz; sc += 1.f; }
            }
#pragma unroll
            for (int m = 1; m < 64; m <<= 1) {
                ss += __shfl_xor(ss, m, 64);
                sc += __shfl_xor(sc, m, 64);
            }
            tau = (ss - 1.0f) / sc;
            if (sc == prev) break;
            prev = sc;
        }
        for (int i = 0; i < ROWS / 64; ++i) {
            const long r = lane + i * 64;
            const float zz = s * x[r * COLS + col];
            if (zz > tau) out[r * COLS + col] = zz - tau;
        }
    }
}

extern "C" void kernel_launch(void* const* d_in, const int* in_sizes, int n_in,
                              void* d_out, int out_size, void* d_ws, size_t ws_size,
                              hipStream_t stream) {
    const float* x = (const float*)d_in[0];
    const float* a = (const float*)d_in[1];
    float* out = (float*)d_out;

    float* pminx = (float*)d_ws;                     // 8 MiB

    // pure-write stream first (R10 lesson: never mix it into a read pass)
    hipMemsetAsync(out, 0, (size_t)ROWS * COLS * sizeof(float), stream);
    hipLaunchKernelGGL(k_pmax, dim3(NSLAB), dim3(1024), 0, stream, x, pminx);
    hipLaunchKernelGGL(k_solve, dim3(COLS / 4), dim3(256), 0, stream,
                       x, a, pminx, out);
}